// Round 11
// baseline (264.807 us; speedup 1.0000x reference)
//
#include <hip/hip_runtime.h>

#define BB  4
#define CC  64
#define HH  128
#define WW  128
#define KS  21
#define PAD 10
#define HWs (HH*WW)
#define LROW 160           // 128 cols + 12 left pad + 20 right pad
#define LBUF (8*LROW)      // floats per buffer (8 rows)

typedef float f32x4n __attribute__((ext_vector_type(4)));

// Block: 512 threads = 2 dj-groups x (8 rows x 32 quads). Group 0: dj 0..10,
// group 1: dj 10..20 (dj=10 computed by both, stored by group 0 only).
// Each group double-buffers its OWN copy of the 8 f2 rows in LDS; wave w
// stages and reads only its own 2 rows -> all LDS sharing is intra-wave:
// NO barriers (per-wave in-order DS execution; sched_barrier(0) stops the
// compiler reordering DS ops that alias only across lanes).
// acc[4][11] = 44 regs/thread -> fits arch VGPRs, no AGPR shuttling.
__global__ __launch_bounds__(512, 4) void corr_kernel(
    const float* __restrict__ feat1,
    const float* __restrict__ feat2,
    float* __restrict__ out)
{
    __shared__ __align__(16) float lds[4*LBUF];   // [group][buf][8][LROW]

    const int tid = threadIdx.x;
    const int g   = tid >> 8;          // dj-half group (wave-uniform)
    const int t   = tid & 255;

    // XCD-chunked swizzle: 1344 = 8*168. XCD x gets work-ids [168x,168x+168):
    // one batch's 8 h8-octets x 21 di -> f1 tile + f2 halo (~4.8 MB) live in
    // that XCD's L2 instead of being re-fetched 21x from HBM.
    const int nwg = BB * (HH/8) * KS;  // 1344
    int bi = (blockIdx.x & 7) * (nwg >> 3) + (blockIdx.x >> 3);

    const int di = bi % KS;  bi /= KS;
    const int h8 = bi % (HH/8);
    const int b  = bi / (HH/8);

    const int row = t >> 5;            // 0..7 within octet
    const int q   = t & 31;
    const int h   = h8*8 + row;
    const int w0  = q << 2;            // 4 consecutive pixels
    const int rr  = h + di - PAD;      // feat2 source row
    const bool valid = (rr >= 0) && (rr < HH);
    const int rc  = valid ? rr : 0;    // clamped (masked lanes never load)

    float* gb = &lds[(g*2)*LBUF];
    // zero pad columns (L in [0,12) U [140,160)) of this wave's rows, both buffers
    { const int L = (q < 12) ? q : (q + 128);
      gb[row*LROW + L]        = 0.0f;
      gb[LBUF + row*LROW + L] = 0.0f; }

    float acc[4][11];
#pragma unroll
    for (int p = 0; p < 4; ++p)
#pragma unroll
        for (int j = 0; j < 11; ++j) acc[p][j] = 0.0f;

    if (__ballot(valid) != 0ull) {
        const float* f1p = feat1 + (((ptrdiff_t)(b*CC)*HH + h)*WW + w0);
        const float* f2p = feat2 + (((ptrdiff_t)(b*CC)*HH + rc)*WW + w0);

        float*       lw = gb + row*LROW + 12 + w0;   // stage own quad at L=w0+12
        const float* lr = gb + row*LROW + w0;        // L=w0 corresponds to col w0-12

        float4 vcur = make_float4(0.f,0.f,0.f,0.f);
        float4 vnxt = make_float4(0.f,0.f,0.f,0.f);
        if (valid) {
            vcur = *(const float4*)(f2p);
            vnxt = *(const float4*)(f2p + HWs);
        }
        float4 a = *(const float4*)(f1p);

        *(float4*)lw = vcur;                    // stage c=0 into buf0
        __builtin_amdgcn_sched_barrier(0);      // pad/stage writes precede window reads

#pragma unroll 2
        for (int c = 0; c < CC; ++c) {
            // ---- global prefetch (issue early; latency hidden under FMAs) ----
            float4 an  = a;
            float4 vld = make_float4(0.f,0.f,0.f,0.f);
            if (c + 1 < CC) an = *(const float4*)(f1p + HWs);
            if (valid && (c + 2 < CC)) vld = *(const float4*)(f2p + 2*HWs);

            // ---- LDS window for current c ----
            // win[k]: g0 -> col w0-10+k, g1 -> col w0+k. Both: FMA uses win[p+j].
            const float* lrb = lr + ((c & 1) ? LBUF : 0);
            float win[14];
            if (g == 0) {
                const float2 wl = *(const float2*)(lrb + 2);   // cols w0-10,w0-9
                const float4 wa = *(const float4*)(lrb + 4);   // cols w0-8..w0-5
                const float4 wb = *(const float4*)(lrb + 8);   // cols w0-4..w0-1
                win[0]=wl.x;  win[1]=wl.y;
                win[2]=wa.x;  win[3]=wa.y;  win[4]=wa.z;  win[5]=wa.w;
                win[6]=wb.x;  win[7]=wb.y;  win[8]=wb.z;  win[9]=wb.w;
                win[10]=vcur.x; win[11]=vcur.y; win[12]=vcur.z; win[13]=vcur.w;
            } else {
                const float4 wa = *(const float4*)(lrb + 16);  // cols w0+4..w0+7
                const float4 wb = *(const float4*)(lrb + 20);  // cols w0+8..w0+11
                const float2 wl = *(const float2*)(lrb + 24);  // cols w0+12,w0+13
                win[0]=vcur.x; win[1]=vcur.y; win[2]=vcur.z; win[3]=vcur.w;
                win[4]=wa.x;  win[5]=wa.y;  win[6]=wa.z;  win[7]=wa.w;
                win[8]=wb.x;  win[9]=wb.y;  win[10]=wb.z; win[11]=wb.w;
                win[12]=wl.x; win[13]=wl.y;
            }

            // ---- stage c+1 into the other buffer ----
            *(float4*)(lw + ((c & 1) ? 0 : LBUF)) = vnxt;
            __builtin_amdgcn_sched_barrier(0);   // keep this write below the reads above

            // pixel p, local j: g0 dj=j, g1 dj=10+j; f2 col = w0+p+dj-10 -> win[p+j]
#pragma unroll
            for (int j = 0; j < 11; ++j) {
                acc[0][j] += a.x * win[j + 0];
                acc[1][j] += a.y * win[j + 1];
                acc[2][j] += a.z * win[j + 2];
                acc[3][j] += a.w * win[j + 3];
            }

            a = an; vcur = vnxt; vnxt = vld;
            f1p += HWs; f2p += HWs;
        }
    }

    const float scale = 1.0f / (float)CC;
    const int djb = 10 * g;
    float* op = out + ((((ptrdiff_t)b*(KS*KS) + (ptrdiff_t)(di*KS + djb))*HH + h)*WW + w0);
#pragma unroll
    for (int j = 0; j < 11; ++j) {
        if (g == 1 && j == 0) continue;   // dj=10 stored by group 0
        f32x4n v = { acc[0][j]*scale, acc[1][j]*scale,
                     acc[2][j]*scale, acc[3][j]*scale };
        __builtin_nontemporal_store(v, (f32x4n*)(op + (ptrdiff_t)j*HWs));
    }
}

extern "C" void kernel_launch(void* const* d_in, const int* in_sizes, int n_in,
                              void* d_out, int out_size, void* d_ws, size_t ws_size,
                              hipStream_t stream) {
    const float* feat1 = (const float*)d_in[0];
    const float* feat2 = (const float*)d_in[1];
    float* out = (float*)d_out;

    const int blocks = BB * (HH / 8) * KS;   // 1344
    corr_kernel<<<blocks, 512, 0, stream>>>(feat1, feat2, out);
}